// Round 1
// baseline (7002.226 us; speedup 1.0000x reference)
//
#include <hip/hip_runtime.h>
#include <math.h>

#define N_ 8
#define L_ 1024
#define H_ 16
#define E_ 1024
#define D_ 64

static constexpr size_t NHLD = (size_t)N_ * H_ * L_ * D_; // 8388608

// ---------------------------------------------------------------------------
// Kernel 1: QKV projection. x:(N,L,E) f32 -> q,k,v:(N,H,L,D) f32
// One block per (n,l). z row (1024 f32) staged in LDS; weights read as float4
// from global (16 KB each, L1-resident).
// ---------------------------------------------------------------------------
__global__ __launch_bounds__(256) void qkv_kernel(
    const float* __restrict__ x,
    const float* __restrict__ Wq, const float* __restrict__ bq,
    const float* __restrict__ Wk, const float* __restrict__ bk,
    const float* __restrict__ Wv, const float* __restrict__ bv,
    float* __restrict__ qo, float* __restrict__ ko, float* __restrict__ vo)
{
    const int bid = blockIdx.x;
    const int n = bid >> 10;      // / L_
    const int l = bid & 1023;
    const int t = threadIdx.x;
    __shared__ float zs[E_];
    ((float4*)zs)[t] = ((const float4*)(x + ((size_t)n * L_ + l) * E_))[t];
    __syncthreads();
    #pragma unroll
    for (int j = 0; j < 4; ++j) {
        const int e = t + j * 256;
        const int h = e >> 6, dp = e & 63;
        float aq = bq[dp], ak = bk[dp], av = bv[dp];
        const float4* wq4 = (const float4*)(Wq + dp * D_);
        const float4* wk4 = (const float4*)(Wk + dp * D_);
        const float4* wv4 = (const float4*)(Wv + dp * D_);
        const float* z = zs + h * D_;
        #pragma unroll
        for (int dd = 0; dd < 16; ++dd) {
            const float4 a = wq4[dd], b = wk4[dd], c = wv4[dd];
            const float z0 = z[dd*4+0], z1 = z[dd*4+1], z2 = z[dd*4+2], z3 = z[dd*4+3];
            aq += a.x*z0 + a.y*z1 + a.z*z2 + a.w*z3;
            ak += b.x*z0 + b.y*z1 + b.z*z2 + b.w*z3;
            av += c.x*z0 + c.y*z1 + c.z*z2 + c.w*z3;
        }
        const size_t oidx = (((size_t)n * H_ + h) * L_ + l) * D_ + dp;
        qo[oidx] = aq; ko[oidx] = ak; vo[oidx] = av;
    }
}

// ---------------------------------------------------------------------------
// Kernel 2: fused attention per (n,h,q-tile of 64 rows).
// out_row = softmax(q.K^T/32) @ V  +  S @ V
// where S[q,k] = (k<=q) ? dot(q_row, Erel[k + L-1 - q]) : 0   (skew trick).
// Thread (qr = t>>2, dg = t&3) owns output row qr, d-columns dg*16..dg*16+15.
// Scores: 16-wide partial dots + 4-lane shfl butterfly (no score LDS buffer).
// ---------------------------------------------------------------------------
#define ACC16(P, KI) do { \
    const float4 a0 = *((const float4*)&vs[KI][dg*16]);      \
    const float4 a1 = *((const float4*)&vs[KI][dg*16 + 4]);  \
    const float4 a2 = *((const float4*)&vs[KI][dg*16 + 8]);  \
    const float4 a3 = *((const float4*)&vs[KI][dg*16 + 12]); \
    O[0]  += (P)*a0.x; O[1]  += (P)*a0.y; O[2]  += (P)*a0.z; O[3]  += (P)*a0.w; \
    O[4]  += (P)*a1.x; O[5]  += (P)*a1.y; O[6]  += (P)*a1.z; O[7]  += (P)*a1.w; \
    O[8]  += (P)*a2.x; O[9]  += (P)*a2.y; O[10] += (P)*a2.z; O[11] += (P)*a2.w; \
    O[12] += (P)*a3.x; O[13] += (P)*a3.y; O[14] += (P)*a3.z; O[15] += (P)*a3.w; \
} while (0)

__global__ __launch_bounds__(256) void attn_kernel(
    const float* __restrict__ q, const float* __restrict__ k,
    const float* __restrict__ v, const float* __restrict__ Erel,
    float* __restrict__ attn)
{
    const int bid = blockIdx.x;
    const int qt = bid & 15;
    const int h  = (bid >> 4) & 15;
    const int n  = bid >> 8;
    const int q0 = qt * 64;
    const int t  = threadIdx.x;
    const int qr = t >> 2;
    const int dg = t & 3;
    const int lanebase = (t & 63) & ~3;

    __shared__ float ks[64][68];
    __shared__ float vs[64][68];

    const size_t headoff = ((size_t)n * H_ + h) * L_ * D_;
    const float* kbase = k + headoff;
    const float* vbase = v + headoff;

    // q fragment: row q0+qr, columns dg*16 .. dg*16+15
    float4 qf[4];
    {
        const float4* qp = (const float4*)(q + headoff + (size_t)(q0 + qr) * D_ + dg * 16);
        #pragma unroll
        for (int i = 0; i < 4; ++i) qf[i] = qp[i];
    }

    float O[16];
    #pragma unroll
    for (int j = 0; j < 16; ++j) O[j] = 0.f;
    float mrow = -INFINITY, lsum = 0.f;
    const float scale = 0.03125f; // 1/sqrt(E)=1/32

    // ---- Phase A: online-softmax(QK^T) @ V ----
    for (int kt = 0; kt < 16; ++kt) {
        __syncthreads();
        const float4* kg = (const float4*)(kbase + (size_t)kt * 64 * D_);
        const float4* vg = (const float4*)(vbase + (size_t)kt * 64 * D_);
        #pragma unroll
        for (int i = 0; i < 4; ++i) {
            const int idx = t + i * 256;
            const int row = idx >> 4, c4 = idx & 15;
            *((float4*)&ks[row][c4 * 4]) = kg[idx];
            *((float4*)&vs[row][c4 * 4]) = vg[idx];
        }
        __syncthreads();

        float sreg[16];
        #pragma unroll
        for (int i = 0; i < 16; ++i) {
            #pragma unroll
            for (int g = 0; g < 4; ++g) {
                const int ki = 4 * i + g;
                const float4* kr = (const float4*)&ks[ki][dg * 16];
                float p = 0.f;
                #pragma unroll
                for (int d4 = 0; d4 < 4; ++d4) {
                    const float4 a = qf[d4], b = kr[d4];
                    p += a.x*b.x + a.y*b.y + a.z*b.z + a.w*b.w;
                }
                p += __shfl_xor(p, 1, 64);
                p += __shfl_xor(p, 2, 64);
                if (g == dg) sreg[i] = p * scale;
            }
        }
        // online softmax update (stats duplicated across the 4 dg threads)
        float mt = sreg[0];
        #pragma unroll
        for (int i = 1; i < 16; ++i) mt = fmaxf(mt, sreg[i]);
        mt = fmaxf(mt, __shfl_xor(mt, 1, 64));
        mt = fmaxf(mt, __shfl_xor(mt, 2, 64));
        const float nm = fmaxf(mrow, mt);
        const float alpha = __expf(mrow - nm); // first tile: exp(-inf)=0
        float e[16], esum = 0.f;
        #pragma unroll
        for (int i = 0; i < 16; ++i) { e[i] = __expf(sreg[i] - nm); esum += e[i]; }
        esum += __shfl_xor(esum, 1, 64);
        esum += __shfl_xor(esum, 2, 64);
        lsum = lsum * alpha + esum;
        #pragma unroll
        for (int j = 0; j < 16; ++j) O[j] *= alpha;
        #pragma unroll
        for (int i = 0; i < 16; ++i) {
            const float ei = e[i];
            #pragma unroll
            for (int g = 0; g < 4; ++g) {
                const float p = __shfl(ei, lanebase + g, 64); // exp for ki=4i+g
                const int ki = 4 * i + g;
                ACC16(p, ki);
            }
        }
        mrow = nm;
    }
    const float invl = 1.0f / lsum;
    #pragma unroll
    for (int j = 0; j < 16; ++j) O[j] *= invl;

    // ---- Phase B: += S @ V  (tiles with kt > qt are entirely zero) ----
    const int qg = q0 + qr;
    for (int kt = 0; kt <= qt; ++kt) {
        __syncthreads();
        const float4* vg = (const float4*)(vbase + (size_t)kt * 64 * D_);
        #pragma unroll
        for (int i = 0; i < 4; ++i) {
            const int idx = t + i * 256;
            const int row = idx >> 4, c4 = idx & 15;
            *((float4*)&vs[row][c4 * 4]) = vg[idx];
        }
        __syncthreads();

        float sreg[16];
        #pragma unroll
        for (int i = 0; i < 16; ++i) {
            #pragma unroll
            for (int g = 0; g < 4; ++g) {
                const int ki = 4 * i + g;
                const int kgl = kt * 64 + ki;
                float p = 0.f;
                if (kgl <= qg) {
                    const int tix = kgl + (L_ - 1) - qg; // Erel row, in [0, L)
                    const float4* er = (const float4*)(Erel + (size_t)tix * D_ + dg * 16);
                    #pragma unroll
                    for (int d4 = 0; d4 < 4; ++d4) {
                        const float4 a = qf[d4], b = er[d4];
                        p += a.x*b.x + a.y*b.y + a.z*b.z + a.w*b.w;
                    }
                }
                p += __shfl_xor(p, 1, 64);
                p += __shfl_xor(p, 2, 64);
                if (g == dg) sreg[i] = p; // NOT scaled (S added after softmax)
            }
        }
        #pragma unroll
        for (int i = 0; i < 16; ++i) {
            const float si = sreg[i];
            #pragma unroll
            for (int g = 0; g < 4; ++g) {
                const float p = __shfl(si, lanebase + g, 64);
                const int ki = 4 * i + g;
                ACC16(p, ki);
            }
        }
    }

    float* op = attn + ((size_t)n * L_ + q0 + qr) * E_ + h * 64 + dg * 16;
    ((float4*)op)[0] = make_float4(O[0],  O[1],  O[2],  O[3]);
    ((float4*)op)[1] = make_float4(O[4],  O[5],  O[6],  O[7]);
    ((float4*)op)[2] = make_float4(O[8],  O[9],  O[10], O[11]);
    ((float4*)op)[3] = make_float4(O[12], O[13], O[14], O[15]);
}

// ---------------------------------------------------------------------------
// Kernel 3: output projection. attn:(N*L, E) @ Wo^T + bo -> out:(N*L, E)
// 64x64 C tile per block; Wo tile transposed into LDS so the inner loop is
// float4 LDS reads + 16 FMA per element.
// ---------------------------------------------------------------------------
__global__ __launch_bounds__(256) void proj_kernel(
    const float* __restrict__ A, const float* __restrict__ Wo,
    const float* __restrict__ bo, float* __restrict__ out)
{
    const int bid = blockIdx.x;
    const int rt = bid >> 4, ct = bid & 15;
    const int r0 = rt * 64, c0 = ct * 64;
    const int t = threadIdx.x;
    const int ri = t >> 2, ci0 = (t & 3) * 16;
    __shared__ float As[64][68];
    __shared__ float Wt[64][68]; // Wt[e_local][c_local] = Wo[c0+c][e0+e]
    float acc[16];
    #pragma unroll
    for (int j = 0; j < 16; ++j) acc[j] = 0.f;

    for (int et = 0; et < 16; ++et) {
        const int e0 = et * 64;
        __syncthreads();
        #pragma unroll
        for (int i = 0; i < 4; ++i) {
            const int idx = t + i * 256;
            const int row = idx >> 4, c4 = idx & 15;
            *((float4*)&As[row][c4 * 4]) =
                *((const float4*)(A + (size_t)(r0 + row) * E_ + e0 + c4 * 4));
            const float4 w =
                *((const float4*)(Wo + (size_t)(c0 + row) * E_ + e0 + c4 * 4));
            Wt[c4*4 + 0][row] = w.x;
            Wt[c4*4 + 1][row] = w.y;
            Wt[c4*4 + 2][row] = w.z;
            Wt[c4*4 + 3][row] = w.w;
        }
        __syncthreads();
        #pragma unroll 8
        for (int e = 0; e < 64; ++e) {
            const float a = As[ri][e];
            const float4 w0 = *((const float4*)&Wt[e][ci0]);
            const float4 w1 = *((const float4*)&Wt[e][ci0 + 4]);
            const float4 w2 = *((const float4*)&Wt[e][ci0 + 8]);
            const float4 w3 = *((const float4*)&Wt[e][ci0 + 12]);
            acc[0]  += a*w0.x; acc[1]  += a*w0.y; acc[2]  += a*w0.z; acc[3]  += a*w0.w;
            acc[4]  += a*w1.x; acc[5]  += a*w1.y; acc[6]  += a*w1.z; acc[7]  += a*w1.w;
            acc[8]  += a*w2.x; acc[9]  += a*w2.y; acc[10] += a*w2.z; acc[11] += a*w2.w;
            acc[12] += a*w3.x; acc[13] += a*w3.y; acc[14] += a*w3.z; acc[15] += a*w3.w;
        }
    }
    const float* bop = bo + c0 + ci0;
    float* op = out + (size_t)(r0 + ri) * E_ + c0 + ci0;
    ((float4*)op)[0] = make_float4(acc[0]+bop[0],  acc[1]+bop[1],  acc[2]+bop[2],  acc[3]+bop[3]);
    ((float4*)op)[1] = make_float4(acc[4]+bop[4],  acc[5]+bop[5],  acc[6]+bop[6],  acc[7]+bop[7]);
    ((float4*)op)[2] = make_float4(acc[8]+bop[8],  acc[9]+bop[9],  acc[10]+bop[10], acc[11]+bop[11]);
    ((float4*)op)[3] = make_float4(acc[12]+bop[12], acc[13]+bop[13], acc[14]+bop[14], acc[15]+bop[15]);
}

// ---------------------------------------------------------------------------
extern "C" void kernel_launch(void* const* d_in, const int* in_sizes, int n_in,
                              void* d_out, int out_size, void* d_ws, size_t ws_size,
                              hipStream_t stream)
{
    const float* x    = (const float*)d_in[0];
    const float* Wq   = (const float*)d_in[1];
    const float* bq   = (const float*)d_in[2];
    const float* Wk   = (const float*)d_in[3];
    const float* bk   = (const float*)d_in[4];
    const float* Wv   = (const float*)d_in[5];
    const float* bv   = (const float*)d_in[6];
    const float* Erel = (const float*)d_in[7];
    const float* Wo   = (const float*)d_in[8];
    const float* bo   = (const float*)d_in[9];
    float* out = (float*)d_out;

    float* ws = (float*)d_ws;
    float* q    = ws;                 // (N,H,L,D)
    float* k    = ws + NHLD;          // (N,H,L,D)
    float* v    = ws + 2 * NHLD;      // (N,H,L,D)
    float* attn = ws + 3 * NHLD;      // (N,L,E)

    qkv_kernel<<<N_ * L_, 256, 0, stream>>>(x, Wq, bq, Wk, bk, Wv, bv, q, k, v);
    attn_kernel<<<N_ * H_ * (L_ / 64), 256, 0, stream>>>(q, k, v, Erel, attn);
    proj_kernel<<<(N_ * L_ / 64) * (E_ / 64), 256, 0, stream>>>(attn, Wo, bo, out);
}

// Round 2
// 398.487 us; speedup vs baseline: 17.5720x; 17.5720x over previous
//
#include <hip/hip_runtime.h>
#include <math.h>

#define N_ 8
#define L_ 1024
#define H_ 16
#define E_ 1024
#define D_ 64

typedef __bf16 bf16x8 __attribute__((ext_vector_type(8)));
typedef __bf16 bf16x4 __attribute__((ext_vector_type(4)));
typedef float  f32x4  __attribute__((ext_vector_type(4)));

#define MFMA16(a, b, c) __builtin_amdgcn_mfma_f32_16x16x32_bf16((a), (b), (c), 0, 0, 0)

// ---------------------------------------------------------------------------
// prep: convert Wo (1M) and Erel (64K) f32 -> bf16 scratch.
// ---------------------------------------------------------------------------
__global__ __launch_bounds__(256) void prep_kernel(
    const float* __restrict__ Wo, const float* __restrict__ Erel,
    __bf16* __restrict__ wobf, __bf16* __restrict__ erbf)
{
    const int idx = blockIdx.x * 256 + threadIdx.x;
    const float* src;
    __bf16* dst;
    int off;
    if (blockIdx.x < 1024) { src = Wo;   dst = wobf; off = idx * 4; }
    else                   { src = Erel; dst = erbf; off = (idx - 1024 * 256) * 4; }
    const float4 f = *(const float4*)(src + off);
    bf16x4 h;
    h[0] = (__bf16)f.x; h[1] = (__bf16)f.y; h[2] = (__bf16)f.z; h[3] = (__bf16)f.w;
    *(bf16x4*)(dst + off) = h;
}

// ---------------------------------------------------------------------------
// qkv: x viewed as (131072 x 64) row-major (rows m=(n,l,h)); q/k/v = x @ W^T + b
// written bf16 at flat m*64+d == (n,l,h,d). One block = 64 M-rows; MFMA.
// ---------------------------------------------------------------------------
__global__ __launch_bounds__(256) void qkv_kernel(
    const float* __restrict__ x,
    const float* __restrict__ Wq, const float* __restrict__ bq,
    const float* __restrict__ Wk, const float* __restrict__ bk,
    const float* __restrict__ Wv, const float* __restrict__ bv,
    __bf16* __restrict__ qo, __bf16* __restrict__ ko, __bf16* __restrict__ vo)
{
    const int t = threadIdx.x, w = t >> 6, lane = t & 63;
    const int quad = lane >> 4, l16 = lane & 15;
    const int m0 = blockIdx.x * 64;

    __shared__ __bf16 xs[64][72];
    __shared__ __bf16 wls[3][64][72];

    #pragma unroll
    for (int i = 0; i < 4; ++i) {
        const int idx = t + i * 256, row = idx >> 4, c4 = idx & 15;
        {
            const float4 f = *(const float4*)(x + (size_t)(m0 + row) * 64 + c4 * 4);
            bf16x4 hh; hh[0]=(__bf16)f.x; hh[1]=(__bf16)f.y; hh[2]=(__bf16)f.z; hh[3]=(__bf16)f.w;
            *(bf16x4*)&xs[row][c4 * 4] = hh;
        }
        {
            const float4 f = *(const float4*)(Wq + (size_t)row * 64 + c4 * 4);
            bf16x4 hh; hh[0]=(__bf16)f.x; hh[1]=(__bf16)f.y; hh[2]=(__bf16)f.z; hh[3]=(__bf16)f.w;
            *(bf16x4*)&wls[0][row][c4 * 4] = hh;
        }
        {
            const float4 f = *(const float4*)(Wk + (size_t)row * 64 + c4 * 4);
            bf16x4 hh; hh[0]=(__bf16)f.x; hh[1]=(__bf16)f.y; hh[2]=(__bf16)f.z; hh[3]=(__bf16)f.w;
            *(bf16x4*)&wls[1][row][c4 * 4] = hh;
        }
        {
            const float4 f = *(const float4*)(Wv + (size_t)row * 64 + c4 * 4);
            bf16x4 hh; hh[0]=(__bf16)f.x; hh[1]=(__bf16)f.y; hh[2]=(__bf16)f.z; hh[3]=(__bf16)f.w;
            *(bf16x4*)&wls[2][row][c4 * 4] = hh;
        }
    }
    __syncthreads();

    bf16x8 a[2];
    a[0] = *(const bf16x8*)&xs[w * 16 + l16][quad * 8];
    a[1] = *(const bf16x8*)&xs[w * 16 + l16][32 + quad * 8];

    f32x4 acc[12];
    const f32x4 zero4 = {0.f, 0.f, 0.f, 0.f};
    #pragma unroll
    for (int nt = 0; nt < 12; ++nt) acc[nt] = zero4;

    #pragma unroll
    for (int nt = 0; nt < 12; ++nt) {
        const int sel = nt >> 2, dt = nt & 3;
        #pragma unroll
        for (int c = 0; c < 2; ++c) {
            const bf16x8 b = *(const bf16x8*)&wls[sel][dt * 16 + l16][c * 32 + quad * 8];
            acc[nt] = MFMA16(a[c], b, acc[nt]);
        }
    }

    const float* bias[3] = {bq, bk, bv};
    __bf16* outp[3] = {qo, ko, vo};
    #pragma unroll
    for (int nt = 0; nt < 12; ++nt) {
        const int sel = nt >> 2, dt = nt & 3;
        const float bb = bias[sel][dt * 16 + l16];
        #pragma unroll
        for (int r = 0; r < 4; ++r) {
            const int m = m0 + w * 16 + quad * 4 + r;
            outp[sel][(size_t)m * 64 + dt * 16 + l16] = (__bf16)(acc[nt][r] + bb);
        }
    }
}

// ---------------------------------------------------------------------------
// attn: per (n,h,64 q-rows). out_row = softmax(QK^T/32)@V + S@V, flash-style.
// S[q,k] = (k<=q) ? QE[q, k+1023-q] : 0, with QE = Q @ Erel^T (skew applied
// during the C-frag -> LDS scatter).
// ---------------------------------------------------------------------------
__global__ __launch_bounds__(256) void attn_kernel(
    const __bf16* __restrict__ qbf, const __bf16* __restrict__ kbf,
    const __bf16* __restrict__ vbf, const __bf16* __restrict__ erbf,
    __bf16* __restrict__ attnA)
{
    const int bid = blockIdx.x;
    const int qt = bid & 15, h = (bid >> 4) & 15, n = bid >> 8;
    const int q0 = qt * 64;
    const int t = threadIdx.x, w = t >> 6, lane = t & 63;
    const int quad = lane >> 4, l16 = lane & 15;

    __shared__ __bf16 ks[64][72];   // K tile, row-major (k, d)
    __shared__ __bf16 vt[64][72];   // V tile transposed: vt[d][k]
    __shared__ __bf16 ps[64][72];   // exp-P tile (wave-private 16-row slices)
    __shared__ __bf16 rs[64][72];   // skewed rel tile (wave-private slices)

    // Q A-frags for this wave's 16 rows (layout (n,l,h,d))
    const size_t qrowoff = ((size_t)(n * L_ + q0 + w * 16 + l16) * H_ + h) * D_;
    bf16x8 qa[2];
    qa[0] = *(const bf16x8*)(qbf + qrowoff + quad * 8);
    qa[1] = *(const bf16x8*)(qbf + qrowoff + 32 + quad * 8);

    const f32x4 zero4 = {0.f, 0.f, 0.f, 0.f};
    f32x4 Os[4], Or[4];
    #pragma unroll
    for (int nt = 0; nt < 4; ++nt) { Os[nt] = zero4; Or[nt] = zero4; }
    float m[4], l[4];
    #pragma unroll
    for (int r = 0; r < 4; ++r) { m[r] = -INFINITY; l[r] = 0.f; }

    for (int kt = 0; kt < 16; ++kt) {
        const int k0 = kt * 64;
        __syncthreads();
        // stage K tile (row-major) -- 16B per thread x2
        #pragma unroll
        for (int i = 0; i < 2; ++i) {
            const int idx = t + i * 256, row = idx >> 3, c8 = idx & 7;
            *(float4*)&ks[row][c8 * 8] =
                *(const float4*)(kbf + ((size_t)(n * L_ + k0 + row) * H_ + h) * D_ + c8 * 8);
        }
        // stage V transposed
        #pragma unroll
        for (int i = 0; i < 4; ++i) {
            const int idx = t + i * 256, row = idx >> 4, dc = idx & 15;
            union { float2 f; __bf16 hv[4]; } u;
            u.f = *(const float2*)(vbf + ((size_t)(n * L_ + k0 + row) * H_ + h) * D_ + dc * 4);
            vt[dc * 4 + 0][row] = u.hv[0];
            vt[dc * 4 + 1][row] = u.hv[1];
            vt[dc * 4 + 2][row] = u.hv[2];
            vt[dc * 4 + 3][row] = u.hv[3];
        }
        __syncthreads();

        // ---- S = Q K^T, scaled ----
        f32x4 sc[4];
        #pragma unroll
        for (int nt = 0; nt < 4; ++nt) {
            f32x4 acc = zero4;
            #pragma unroll
            for (int c = 0; c < 2; ++c) {
                const bf16x8 b = *(const bf16x8*)&ks[nt * 16 + l16][c * 32 + quad * 8];
                acc = MFMA16(qa[c], b, acc);
            }
            sc[nt] = acc * 0.03125f;
        }

        // ---- online softmax ----
        float mt[4];
        #pragma unroll
        for (int r = 0; r < 4; ++r)
            mt[r] = fmaxf(fmaxf(sc[0][r], sc[1][r]), fmaxf(sc[2][r], sc[3][r]));
        #pragma unroll
        for (int r = 0; r < 4; ++r) {
            mt[r] = fmaxf(mt[r], __shfl_xor(mt[r], 1, 64));
            mt[r] = fmaxf(mt[r], __shfl_xor(mt[r], 2, 64));
            mt[r] = fmaxf(mt[r], __shfl_xor(mt[r], 4, 64));
            mt[r] = fmaxf(mt[r], __shfl_xor(mt[r], 8, 64));
        }
        float alpha[4], esum[4];
        #pragma unroll
        for (int r = 0; r < 4; ++r) {
            const float mn = fmaxf(m[r], mt[r]);
            alpha[r] = __expf(m[r] - mn);
            m[r] = mn;
            esum[r] = 0.f;
        }
        #pragma unroll
        for (int nt = 0; nt < 4; ++nt)
            #pragma unroll
            for (int r = 0; r < 4; ++r) {
                const float e = __expf(sc[nt][r] - m[r]);
                sc[nt][r] = e;
                esum[r] += e;
            }
        #pragma unroll
        for (int r = 0; r < 4; ++r) {
            esum[r] += __shfl_xor(esum[r], 1, 64);
            esum[r] += __shfl_xor(esum[r], 2, 64);
            esum[r] += __shfl_xor(esum[r], 4, 64);
            esum[r] += __shfl_xor(esum[r], 8, 64);
            l[r] = l[r] * alpha[r] + esum[r];
        }
        #pragma unroll
        for (int nt = 0; nt < 4; ++nt)
            #pragma unroll
            for (int r = 0; r < 4; ++r) Os[nt][r] *= alpha[r];

        // write exp-P to wave-private LDS slice, C-layout scatter
        #pragma unroll
        for (int nt = 0; nt < 4; ++nt)
            #pragma unroll
            for (int r = 0; r < 4; ++r)
                ps[w * 16 + quad * 4 + r][nt * 16 + l16] = (__bf16)sc[nt][r];

        // ---- PV (softmax part) ----
        bf16x8 pa[2];
        pa[0] = *(const bf16x8*)&ps[w * 16 + l16][quad * 8];
        pa[1] = *(const bf16x8*)&ps[w * 16 + l16][32 + quad * 8];
        #pragma unroll
        for (int nt = 0; nt < 4; ++nt)
            #pragma unroll
            for (int c = 0; c < 2; ++c) {
                const bf16x8 b = *(const bf16x8*)&vt[nt * 16 + l16][c * 32 + quad * 8];
                Os[nt] = MFMA16(pa[c], b, Os[nt]);
            }

        // ---- relative-position term (only kt <= qt has unmasked entries) ----
        if (kt <= qt) {
            // QE strip: 16 rows x 80 cols, t_base per wave
            const int tb = k0 - q0 + 1008 - 16 * w;
            f32x4 qe[5];
            #pragma unroll
            for (int st = 0; st < 5; ++st) {
                f32x4 acc = zero4;
                int tr = tb + st * 16 + l16;
                tr = tr > 1023 ? 1023 : tr;  // clamped rows are masked below
                const __bf16* er = erbf + (size_t)tr * 64;
                #pragma unroll
                for (int c = 0; c < 2; ++c) {
                    const bf16x8 b = *(const bf16x8*)(er + c * 32 + quad * 8);
                    acc = MFMA16(qa[c], b, acc);
                }
                qe[st] = acc;
            }
            // skewed scatter: strip col -> kc = col - 15 + row ; mask k<=q
            #pragma unroll
            for (int st = 0; st < 5; ++st)
                #pragma unroll
                for (int r = 0; r < 4; ++r) {
                    const int qrw = quad * 4 + r;
                    const int kc = st * 16 + l16 - 15 + qrw;
                    if (kc >= 0 && kc < 64) {
                        const bool ok = (k0 + kc) <= (q0 + w * 16 + qrw);
                        rs[w * 16 + qrw][kc] = ok ? (__bf16)qe[st][r] : (__bf16)0.0f;
                    }
                }
            bf16x8 ra[2];
            ra[0] = *(const bf16x8*)&rs[w * 16 + l16][quad * 8];
            ra[1] = *(const bf16x8*)&rs[w * 16 + l16][32 + quad * 8];
            #pragma unroll
            for (int nt = 0; nt < 4; ++nt)
                #pragma unroll
                for (int c = 0; c < 2; ++c) {
                    const bf16x8 b = *(const bf16x8*)&vt[nt * 16 + l16][c * 32 + quad * 8];
                    Or[nt] = MFMA16(ra[c], b, Or[nt]);
                }
        }
    }

    // epilogue: out = Os/l + Or -> attnA (n, q, h*64+d) bf16
    #pragma unroll
    for (int nt = 0; nt < 4; ++nt)
        #pragma unroll
        for (int r = 0; r < 4; ++r) {
            const float val = Os[nt][r] / l[r] + Or[nt][r];
            const int qg = q0 + w * 16 + quad * 4 + r;
            attnA[((size_t)(n * L_ + qg)) * E_ + h * 64 + nt * 16 + l16] = (__bf16)val;
        }
}

// ---------------------------------------------------------------------------
// proj: out (8192 x 1024) f32 = attnA (bf16) @ Wo^T (bf16) + bo. 64x64 tiles.
// ---------------------------------------------------------------------------
__global__ __launch_bounds__(256) void proj_kernel(
    const __bf16* __restrict__ A, const __bf16* __restrict__ W,
    const float* __restrict__ bo, float* __restrict__ out)
{
    const int bid = blockIdx.x, rt = bid >> 4, ct = bid & 15;
    const int r0 = rt * 64, c0 = ct * 64;
    const int t = threadIdx.x, w = t >> 6, lane = t & 63;
    const int quad = lane >> 4, l16 = lane & 15;

    __shared__ __bf16 as_[64][72];
    __shared__ __bf16 wsd[64][72];

    const f32x4 zero4 = {0.f, 0.f, 0.f, 0.f};
    f32x4 acc[4];
    #pragma unroll
    for (int nt = 0; nt < 4; ++nt) acc[nt] = zero4;

    for (int kt = 0; kt < 16; ++kt) {
        const int e0 = kt * 64;
        __syncthreads();
        #pragma unroll
        for (int i = 0; i < 2; ++i) {
            const int idx = t + i * 256, row = idx >> 3, c8 = idx & 7;
            *(float4*)&as_[row][c8 * 8] =
                *(const float4*)(A + (size_t)(r0 + row) * E_ + e0 + c8 * 8);
            *(float4*)&wsd[row][c8 * 8] =
                *(const float4*)(W + (size_t)(c0 + row) * E_ + e0 + c8 * 8);
        }
        __syncthreads();
        bf16x8 a0 = *(const bf16x8*)&as_[w * 16 + l16][quad * 8];
        bf16x8 a1 = *(const bf16x8*)&as_[w * 16 + l16][32 + quad * 8];
        #pragma unroll
        for (int nt = 0; nt < 4; ++nt) {
            const bf16x8 b0 = *(const bf16x8*)&wsd[nt * 16 + l16][quad * 8];
            const bf16x8 b1 = *(const bf16x8*)&wsd[nt * 16 + l16][32 + quad * 8];
            acc[nt] = MFMA16(a0, b0, acc[nt]);
            acc[nt] = MFMA16(a1, b1, acc[nt]);
        }
    }

    #pragma unroll
    for (int nt = 0; nt < 4; ++nt) {
        const float bb = bo[c0 + nt * 16 + l16];
        #pragma unroll
        for (int r = 0; r < 4; ++r)
            out[(size_t)(r0 + w * 16 + quad * 4 + r) * E_ + c0 + nt * 16 + l16] =
                acc[nt][r] + bb;
    }
}

// ---------------------------------------------------------------------------
extern "C" void kernel_launch(void* const* d_in, const int* in_sizes, int n_in,
                              void* d_out, int out_size, void* d_ws, size_t ws_size,
                              hipStream_t stream)
{
    const float* x    = (const float*)d_in[0];
    const float* Wq   = (const float*)d_in[1];
    const float* bq   = (const float*)d_in[2];
    const float* Wk   = (const float*)d_in[3];
    const float* bk   = (const float*)d_in[4];
    const float* Wv   = (const float*)d_in[5];
    const float* bv   = (const float*)d_in[6];
    const float* Erel = (const float*)d_in[7];
    const float* Wo   = (const float*)d_in[8];
    const float* bo   = (const float*)d_in[9];
    float* out = (float*)d_out;

    char* p = (char*)d_ws;
    __bf16* qbf   = (__bf16*)p; p += (size_t)N_ * L_ * H_ * D_ * 2;  // 16 MB
    __bf16* kbf   = (__bf16*)p; p += (size_t)N_ * L_ * H_ * D_ * 2;
    __bf16* vbf   = (__bf16*)p; p += (size_t)N_ * L_ * H_ * D_ * 2;
    __bf16* attnA = (__bf16*)p; p += (size_t)N_ * L_ * E_ * 2;       // 16 MB
    __bf16* wobf  = (__bf16*)p; p += (size_t)E_ * E_ * 2;            // 2 MB
    __bf16* erbf  = (__bf16*)p; p += (size_t)L_ * D_ * 2;            // 128 KB

    prep_kernel<<<1088, 256, 0, stream>>>(Wo, Erel, wobf, erbf);
    qkv_kernel<<<(N_ * L_ * H_) / 64, 256, 0, stream>>>(x, Wq, bq, Wk, bk, Wv, bv,
                                                        qbf, kbf, vbf);
    attn_kernel<<<N_ * H_ * (L_ / 64), 256, 0, stream>>>(qbf, kbf, vbf, erbf, attnA);
    proj_kernel<<<(N_ * L_ / 64) * (E_ / 64), 256, 0, stream>>>(attnA, wobf, bo, out);
}

// Round 3
// 357.612 us; speedup vs baseline: 19.5805x; 1.1143x over previous
//
#include <hip/hip_runtime.h>
#include <math.h>

#define N_ 8
#define L_ 1024
#define H_ 16
#define E_ 1024
#define D_ 64

typedef __bf16 bf16x8 __attribute__((ext_vector_type(8)));
typedef __bf16 bf16x4 __attribute__((ext_vector_type(4)));
typedef float  f32x4  __attribute__((ext_vector_type(4)));

#define MFMA16(a, b, c) __builtin_amdgcn_mfma_f32_16x16x32_bf16((a), (b), (c), 0, 0, 0)

// ---------------------------------------------------------------------------
// prep: convert Wo (1M) and Erel (64K) f32 -> bf16 scratch.
// ---------------------------------------------------------------------------
__global__ __launch_bounds__(256) void prep_kernel(
    const float* __restrict__ Wo, const float* __restrict__ Erel,
    __bf16* __restrict__ wobf, __bf16* __restrict__ erbf)
{
    const int idx = blockIdx.x * 256 + threadIdx.x;
    const float* src;
    __bf16* dst;
    int off;
    if (blockIdx.x < 1024) { src = Wo;   dst = wobf; off = idx * 4; }
    else                   { src = Erel; dst = erbf; off = (idx - 1024 * 256) * 4; }
    const float4 f = *(const float4*)(src + off);
    bf16x4 h;
    h[0] = (__bf16)f.x; h[1] = (__bf16)f.y; h[2] = (__bf16)f.z; h[3] = (__bf16)f.w;
    *(bf16x4*)(dst + off) = h;
}

// ---------------------------------------------------------------------------
// qkv: x viewed as (131072 x 64) row-major (rows m=(n,l,h)); q/k/v = x @ W^T + b
// written bf16 at flat m*64+d == (n,l,h,d). One block = 64 M-rows; MFMA.
// ---------------------------------------------------------------------------
__global__ __launch_bounds__(256) void qkv_kernel(
    const float* __restrict__ x,
    const float* __restrict__ Wq, const float* __restrict__ bq,
    const float* __restrict__ Wk, const float* __restrict__ bk,
    const float* __restrict__ Wv, const float* __restrict__ bv,
    __bf16* __restrict__ qo, __bf16* __restrict__ ko, __bf16* __restrict__ vo)
{
    const int t = threadIdx.x, w = t >> 6, lane = t & 63;
    const int quad = lane >> 4, l16 = lane & 15;
    const int m0 = blockIdx.x * 64;

    __shared__ __bf16 xs[64][72];
    __shared__ __bf16 wls[3][64][72];

    #pragma unroll
    for (int i = 0; i < 4; ++i) {
        const int idx = t + i * 256, row = idx >> 4, c4 = idx & 15;
        {
            const float4 f = *(const float4*)(x + (size_t)(m0 + row) * 64 + c4 * 4);
            bf16x4 hh; hh[0]=(__bf16)f.x; hh[1]=(__bf16)f.y; hh[2]=(__bf16)f.z; hh[3]=(__bf16)f.w;
            *(bf16x4*)&xs[row][c4 * 4] = hh;
        }
        {
            const float4 f = *(const float4*)(Wq + (size_t)row * 64 + c4 * 4);
            bf16x4 hh; hh[0]=(__bf16)f.x; hh[1]=(__bf16)f.y; hh[2]=(__bf16)f.z; hh[3]=(__bf16)f.w;
            *(bf16x4*)&wls[0][row][c4 * 4] = hh;
        }
        {
            const float4 f = *(const float4*)(Wk + (size_t)row * 64 + c4 * 4);
            bf16x4 hh; hh[0]=(__bf16)f.x; hh[1]=(__bf16)f.y; hh[2]=(__bf16)f.z; hh[3]=(__bf16)f.w;
            *(bf16x4*)&wls[1][row][c4 * 4] = hh;
        }
        {
            const float4 f = *(const float4*)(Wv + (size_t)row * 64 + c4 * 4);
            bf16x4 hh; hh[0]=(__bf16)f.x; hh[1]=(__bf16)f.y; hh[2]=(__bf16)f.z; hh[3]=(__bf16)f.w;
            *(bf16x4*)&wls[2][row][c4 * 4] = hh;
        }
    }
    __syncthreads();

    bf16x8 a[2];
    a[0] = *(const bf16x8*)&xs[w * 16 + l16][quad * 8];
    a[1] = *(const bf16x8*)&xs[w * 16 + l16][32 + quad * 8];

    f32x4 acc[12];
    const f32x4 zero4 = {0.f, 0.f, 0.f, 0.f};
    #pragma unroll
    for (int nt = 0; nt < 12; ++nt) acc[nt] = zero4;

    #pragma unroll
    for (int nt = 0; nt < 12; ++nt) {
        const int sel = nt >> 2, dt = nt & 3;
        #pragma unroll
        for (int c = 0; c < 2; ++c) {
            const bf16x8 b = *(const bf16x8*)&wls[sel][dt * 16 + l16][c * 32 + quad * 8];
            acc[nt] = MFMA16(a[c], b, acc[nt]);
        }
    }

    const float* bias[3] = {bq, bk, bv};
    __bf16* outp[3] = {qo, ko, vo};
    #pragma unroll
    for (int nt = 0; nt < 12; ++nt) {
        const int sel = nt >> 2, dt = nt & 3;
        const float bb = bias[sel][dt * 16 + l16];
        #pragma unroll
        for (int r = 0; r < 4; ++r) {
            const int m = m0 + w * 16 + quad * 4 + r;
            outp[sel][(size_t)m * 64 + dt * 16 + l16] = (__bf16)(acc[nt][r] + bb);
        }
    }
}

// ---------------------------------------------------------------------------
// attn: per (n,h,64 q-rows). Everything computed TRANSPOSED so softmax state
// is per-lane (lane's l16 = q):
//   S^T = K Q^T (MFMA A=K,B=Q)  -> lane holds 16 keys of one q-column
//   out^T = V^T P^T (A=V^T frag from vt, B=P^T = row-read of normal-layout ps)
// rel term: QE^T = Erel Q^T, skew-scattered to rs (normal layout), same PV^T.
// ---------------------------------------------------------------------------
__global__ __launch_bounds__(256, 4) void attn_kernel(
    const __bf16* __restrict__ qbf, const __bf16* __restrict__ kbf,
    const __bf16* __restrict__ vbf, const __bf16* __restrict__ erbf,
    __bf16* __restrict__ attnA)
{
    const int bid = blockIdx.x;
    // XCD swizzle: the 16 q-tiles of one (n,h) land on one XCD (bid%8 fixed)
    const int p  = (bid & 7) + ((bid >> 7) << 3);   // (n,h) pair id 0..127
    const int qt = (bid >> 3) & 15;
    const int h = p & 15, n = p >> 4;
    const int q0 = qt * 64;
    const int t = threadIdx.x, w = t >> 6, lane = t & 63;
    const int quad = lane >> 4, l16 = lane & 15;

    __shared__ __bf16 ks[64][72];   // K tile row-major (key, d)
    __shared__ __bf16 vt[64][72];   // V^T tile: vt[d][key]
    __shared__ __bf16 ps[64][72];   // exp-P tile, normal layout [q][key]
    __shared__ __bf16 rs[64][72];   // skewed rel tile, normal layout [q][key]

    // Q B-frags for this wave's 16 q rows (layout (n,l,h,d))
    const size_t qrowoff = ((size_t)(n * L_ + q0 + w * 16 + l16) * H_ + h) * D_;
    bf16x8 qa[2];
    qa[0] = *(const bf16x8*)(qbf + qrowoff + quad * 8);
    qa[1] = *(const bf16x8*)(qbf + qrowoff + 32 + quad * 8);

    const f32x4 zero4 = {0.f, 0.f, 0.f, 0.f};
    f32x4 Os[4], Or[4];              // out^T: lane col q=l16, rows d
    #pragma unroll
    for (int nt = 0; nt < 4; ++nt) { Os[nt] = zero4; Or[nt] = zero4; }
    float m = -INFINITY, lsum = 0.f;
    const float scale = 0.03125f;    // 1/sqrt(E)

    // staging addresses (row stride in k/v buffers = H_*D_ = 1024 elements)
    const __bf16* kbase = kbf + ((size_t)n * L_ * H_ + h) * D_;
    const __bf16* vbase = vbf + ((size_t)n * L_ * H_ + h) * D_;
    const int krow0 = t >> 3, kc8 = (t & 7) * 8;          // K: rows t>>3, +32
    const int vkey = t & 63;                               // V: key fast per wave
    const int vd0  = (t >> 6) * 8;                         // wave-uniform d base

    // prefetch tile 0
    float4 kreg[2], vreg[2];
    #pragma unroll
    for (int i = 0; i < 2; ++i) {
        kreg[i] = *(const float4*)(kbase + (size_t)(krow0 + i * 32) * 1024 + kc8);
        vreg[i] = *(const float4*)(vbase + (size_t)vkey * 1024 + vd0 + i * 32);
    }

    for (int kt = 0; kt < 16; ++kt) {
        __syncthreads();             // prior iter's LDS reads complete
        #pragma unroll
        for (int i = 0; i < 2; ++i) {
            *(float4*)&ks[krow0 + i * 32][kc8] = kreg[i];
            union { float4 f; __bf16 hv[8]; } uv;
            uv.f = vreg[i];
            const int d0 = vd0 + i * 32;
            #pragma unroll
            for (int j = 0; j < 8; ++j) vt[d0 + j][vkey] = uv.hv[j];
        }
        __syncthreads();

        if (kt < 15) {               // prefetch next tile (overlaps compute)
            const size_t roff = (size_t)(kt + 1) * 64 * 1024;
            #pragma unroll
            for (int i = 0; i < 2; ++i) {
                kreg[i] = *(const float4*)(kbase + roff + (size_t)(krow0 + i * 32) * 1024 + kc8);
                vreg[i] = *(const float4*)(vbase + roff + (size_t)vkey * 1024 + vd0 + i * 32);
            }
        }

        // ---- S^T = K Q^T (unscaled) ----
        f32x4 sc[4];
        #pragma unroll
        for (int nt = 0; nt < 4; ++nt) {
            f32x4 acc = zero4;
            #pragma unroll
            for (int c = 0; c < 2; ++c) {
                const bf16x8 ka = *(const bf16x8*)&ks[nt * 16 + l16][c * 32 + quad * 8];
                acc = MFMA16(ka, qa[c], acc);
            }
            sc[nt] = acc;
        }

        // ---- online softmax (per-lane: this lane's q = l16 column) ----
        float mt = sc[0][0];
        #pragma unroll
        for (int nt = 0; nt < 4; ++nt)
            #pragma unroll
            for (int r = 0; r < 4; ++r) mt = fmaxf(mt, sc[nt][r]);
        mt = fmaxf(mt, __shfl_xor(mt, 16, 64));
        mt = fmaxf(mt, __shfl_xor(mt, 32, 64));
        const float mn = fmaxf(m, mt);
        const float alpha = __expf((m - mn) * scale);
        float esum = 0.f;
        #pragma unroll
        for (int nt = 0; nt < 4; ++nt)
            #pragma unroll
            for (int r = 0; r < 4; ++r) {
                const float e = __expf((sc[nt][r] - mn) * scale);
                sc[nt][r] = e;
                esum += e;
            }
        esum += __shfl_xor(esum, 16, 64);
        esum += __shfl_xor(esum, 32, 64);
        lsum = lsum * alpha + esum;
        m = mn;
        #pragma unroll
        for (int nt = 0; nt < 4; ++nt) Os[nt] *= alpha;

        // P^T C-frags -> normal-layout ps rows (wave-private row w*16+l16)
        #pragma unroll
        for (int nt = 0; nt < 4; ++nt) {
            bf16x4 pk;
            #pragma unroll
            for (int r = 0; r < 4; ++r) pk[r] = (__bf16)sc[nt][r];
            *(bf16x4*)&ps[w * 16 + l16][nt * 16 + quad * 4] = pk;
        }

        // ---- rel scores (only kt <= qt contributes) ----
        const bool dorel = (kt <= qt);
        if (dorel) {
            const int tb = kt * 64 - q0 + 1008 - 16 * w;   // >= 0 always
            f32x4 qe[5];
            #pragma unroll
            for (int st = 0; st < 5; ++st) {
                int tr = tb + st * 16 + l16;
                tr = tr > 1023 ? 1023 : tr;
                f32x4 acc = zero4;
                #pragma unroll
                for (int c = 0; c < 2; ++c) {
                    const bf16x8 ea = *(const bf16x8*)(erbf + (size_t)tr * 64 + c * 32 + quad * 8);
                    acc = MFMA16(ea, qa[c], acc);
                }
                qe[st] = acc;
            }
            // skew scatter: value (t = tb+st*16+quad*4+r, q-col l16) -> key col
            // kc = st*16+quad*4+r+l16-15 ; mask k<=q  <=>  t <= 1023
            #pragma unroll
            for (int st = 0; st < 5; ++st)
                #pragma unroll
                for (int r = 0; r < 4; ++r) {
                    const int kc = st * 16 + quad * 4 + r + l16 - 15;
                    const int tg = tb + st * 16 + quad * 4 + r;
                    if (kc >= 0 && kc < 64)
                        rs[w * 16 + l16][kc] = (tg <= 1023) ? (__bf16)qe[st][r]
                                                            : (__bf16)0.0f;
                }
        }

        // ---- out^T accumulation: A = V^T frag, B = P^T (ps row) / rel (rs) --
        #pragma unroll
        for (int c = 0; c < 2; ++c) {
            const bf16x8 pb = *(const bf16x8*)&ps[w * 16 + l16][c * 32 + quad * 8];
            bf16x8 rb;
            if (dorel) rb = *(const bf16x8*)&rs[w * 16 + l16][c * 32 + quad * 8];
            #pragma unroll
            for (int nt = 0; nt < 4; ++nt) {
                const bf16x8 va = *(const bf16x8*)&vt[nt * 16 + l16][c * 32 + quad * 8];
                Os[nt] = MFMA16(va, pb, Os[nt]);
                if (dorel) Or[nt] = MFMA16(va, rb, Or[nt]);
            }
        }
    }

    // epilogue: out = Os^T/l + Or^T ; lane col q=l16, rows d=nt*16+quad*4+r
    const float invl = 1.0f / lsum;
    __bf16* obase = attnA + ((size_t)(n * L_ + q0 + w * 16 + l16)) * E_ + h * 64;
    #pragma unroll
    for (int nt = 0; nt < 4; ++nt) {
        bf16x4 ov;
        #pragma unroll
        for (int r = 0; r < 4; ++r)
            ov[r] = (__bf16)(Os[nt][r] * invl + Or[nt][r]);
        *(bf16x4*)(obase + nt * 16 + quad * 4) = ov;
    }
}

// ---------------------------------------------------------------------------
// proj: out (8192 x 1024) f32 = attnA (bf16) @ Wo^T (bf16) + bo. 64x64 tiles.
// ---------------------------------------------------------------------------
__global__ __launch_bounds__(256) void proj_kernel(
    const __bf16* __restrict__ A, const __bf16* __restrict__ W,
    const float* __restrict__ bo, float* __restrict__ out)
{
    const int bid = blockIdx.x, rt = bid >> 4, ct = bid & 15;
    const int r0 = rt * 64, c0 = ct * 64;
    const int t = threadIdx.x, w = t >> 6, lane = t & 63;
    const int quad = lane >> 4, l16 = lane & 15;

    __shared__ __bf16 as_[64][72];
    __shared__ __bf16 wsd[64][72];

    const f32x4 zero4 = {0.f, 0.f, 0.f, 0.f};
    f32x4 acc[4];
    #pragma unroll
    for (int nt = 0; nt < 4; ++nt) acc[nt] = zero4;

    for (int kt = 0; kt < 16; ++kt) {
        const int e0 = kt * 64;
        __syncthreads();
        #pragma unroll
        for (int i = 0; i < 2; ++i) {
            const int idx = t + i * 256, row = idx >> 3, c8 = idx & 7;
            *(float4*)&as_[row][c8 * 8] =
                *(const float4*)(A + (size_t)(r0 + row) * E_ + e0 + c8 * 8);
            *(float4*)&wsd[row][c8 * 8] =
                *(const float4*)(W + (size_t)(c0 + row) * E_ + e0 + c8 * 8);
        }
        __syncthreads();
        bf16x8 a0 = *(const bf16x8*)&as_[w * 16 + l16][quad * 8];
        bf16x8 a1 = *(const bf16x8*)&as_[w * 16 + l16][32 + quad * 8];
        #pragma unroll
        for (int nt = 0; nt < 4; ++nt) {
            const bf16x8 b0 = *(const bf16x8*)&wsd[nt * 16 + l16][quad * 8];
            const bf16x8 b1 = *(const bf16x8*)&wsd[nt * 16 + l16][32 + quad * 8];
            acc[nt] = MFMA16(a0, b0, acc[nt]);
            acc[nt] = MFMA16(a1, b1, acc[nt]);
        }
    }

    #pragma unroll
    for (int nt = 0; nt < 4; ++nt) {
        const float bb = bo[c0 + nt * 16 + l16];
        #pragma unroll
        for (int r = 0; r < 4; ++r)
            out[(size_t)(r0 + w * 16 + quad * 4 + r) * E_ + c0 + nt * 16 + l16] =
                acc[nt][r] + bb;
    }
}

// ---------------------------------------------------------------------------
extern "C" void kernel_launch(void* const* d_in, const int* in_sizes, int n_in,
                              void* d_out, int out_size, void* d_ws, size_t ws_size,
                              hipStream_t stream)
{
    const float* x    = (const float*)d_in[0];
    const float* Wq   = (const float*)d_in[1];
    const float* bq   = (const float*)d_in[2];
    const float* Wk   = (const float*)d_in[3];
    const float* bk   = (const float*)d_in[4];
    const float* Wv   = (const float*)d_in[5];
    const float* bv   = (const float*)d_in[6];
    const float* Erel = (const float*)d_in[7];
    const float* Wo   = (const float*)d_in[8];
    const float* bo   = (const float*)d_in[9];
    float* out = (float*)d_out;

    char* p = (char*)d_ws;
    __bf16* qbf   = (__bf16*)p; p += (size_t)N_ * L_ * H_ * D_ * 2;  // 16 MB
    __bf16* kbf   = (__bf16*)p; p += (size_t)N_ * L_ * H_ * D_ * 2;
    __bf16* vbf   = (__bf16*)p; p += (size_t)N_ * L_ * H_ * D_ * 2;
    __bf16* attnA = (__bf16*)p; p += (size_t)N_ * L_ * E_ * 2;       // 16 MB
    __bf16* wobf  = (__bf16*)p; p += (size_t)E_ * E_ * 2;            // 2 MB
    __bf16* erbf  = (__bf16*)p; p += (size_t)L_ * D_ * 2;            // 128 KB

    prep_kernel<<<1088, 256, 0, stream>>>(Wo, Erel, wobf, erbf);
    qkv_kernel<<<(N_ * L_ * H_) / 64, 256, 0, stream>>>(x, Wq, bq, Wk, bk, Wv, bv,
                                                        qbf, kbf, vbf);
    attn_kernel<<<N_ * H_ * (L_ / 64), 256, 0, stream>>>(qbf, kbf, vbf, erbf, attnA);
    proj_kernel<<<(N_ * L_ / 64) * (E_ / 64), 256, 0, stream>>>(attnA, wobf, bo, out);
}

// Round 4
// 317.546 us; speedup vs baseline: 22.0510x; 1.1262x over previous
//
#include <hip/hip_runtime.h>
#include <math.h>

#define N_ 8
#define L_ 1024
#define H_ 16
#define E_ 1024
#define D_ 64

typedef __bf16 bf16x8 __attribute__((ext_vector_type(8)));
typedef __bf16 bf16x4 __attribute__((ext_vector_type(4)));
typedef float  f32x4  __attribute__((ext_vector_type(4)));

#define MFMA16(a, b, c) __builtin_amdgcn_mfma_f32_16x16x32_bf16((a), (b), (c), 0, 0, 0)

// ---------------------------------------------------------------------------
// prep: convert Wo (1M) and Erel (64K) f32 -> bf16 scratch.
// ---------------------------------------------------------------------------
__global__ __launch_bounds__(256) void prep_kernel(
    const float* __restrict__ Wo, const float* __restrict__ Erel,
    __bf16* __restrict__ wobf, __bf16* __restrict__ erbf)
{
    const int idx = blockIdx.x * 256 + threadIdx.x;
    const float* src;
    __bf16* dst;
    int off;
    if (blockIdx.x < 1024) { src = Wo;   dst = wobf; off = idx * 4; }
    else                   { src = Erel; dst = erbf; off = (idx - 1024 * 256) * 4; }
    const float4 f = *(const float4*)(src + off);
    bf16x4 h;
    h[0] = (__bf16)f.x; h[1] = (__bf16)f.y; h[2] = (__bf16)f.z; h[3] = (__bf16)f.w;
    *(bf16x4*)(dst + off) = h;
}

// ---------------------------------------------------------------------------
// qkv: x viewed as (131072 x 64) row-major (rows m=(n,l,h)); q/k/v = x @ W^T + b
// written bf16 at flat m*64+d == (n,l,h,d). One block = 64 M-rows; MFMA.
// ---------------------------------------------------------------------------
__global__ __launch_bounds__(256) void qkv_kernel(
    const float* __restrict__ x,
    const float* __restrict__ Wq, const float* __restrict__ bq,
    const float* __restrict__ Wk, const float* __restrict__ bk,
    const float* __restrict__ Wv, const float* __restrict__ bv,
    __bf16* __restrict__ qo, __bf16* __restrict__ ko, __bf16* __restrict__ vo)
{
    const int t = threadIdx.x, w = t >> 6, lane = t & 63;
    const int quad = lane >> 4, l16 = lane & 15;
    const int m0 = blockIdx.x * 64;

    __shared__ __bf16 xs[64][72];
    __shared__ __bf16 wls[3][64][72];

    #pragma unroll
    for (int i = 0; i < 4; ++i) {
        const int idx = t + i * 256, row = idx >> 4, c4 = idx & 15;
        {
            const float4 f = *(const float4*)(x + (size_t)(m0 + row) * 64 + c4 * 4);
            bf16x4 hh; hh[0]=(__bf16)f.x; hh[1]=(__bf16)f.y; hh[2]=(__bf16)f.z; hh[3]=(__bf16)f.w;
            *(bf16x4*)&xs[row][c4 * 4] = hh;
        }
        {
            const float4 f = *(const float4*)(Wq + (size_t)row * 64 + c4 * 4);
            bf16x4 hh; hh[0]=(__bf16)f.x; hh[1]=(__bf16)f.y; hh[2]=(__bf16)f.z; hh[3]=(__bf16)f.w;
            *(bf16x4*)&wls[0][row][c4 * 4] = hh;
        }
        {
            const float4 f = *(const float4*)(Wk + (size_t)row * 64 + c4 * 4);
            bf16x4 hh; hh[0]=(__bf16)f.x; hh[1]=(__bf16)f.y; hh[2]=(__bf16)f.z; hh[3]=(__bf16)f.w;
            *(bf16x4*)&wls[1][row][c4 * 4] = hh;
        }
        {
            const float4 f = *(const float4*)(Wv + (size_t)row * 64 + c4 * 4);
            bf16x4 hh; hh[0]=(__bf16)f.x; hh[1]=(__bf16)f.y; hh[2]=(__bf16)f.z; hh[3]=(__bf16)f.w;
            *(bf16x4*)&wls[2][row][c4 * 4] = hh;
        }
    }
    __syncthreads();

    bf16x8 a[2];
    a[0] = *(const bf16x8*)&xs[w * 16 + l16][quad * 8];
    a[1] = *(const bf16x8*)&xs[w * 16 + l16][32 + quad * 8];

    f32x4 acc[12];
    const f32x4 zero4 = {0.f, 0.f, 0.f, 0.f};
    #pragma unroll
    for (int nt = 0; nt < 12; ++nt) acc[nt] = zero4;

    #pragma unroll
    for (int nt = 0; nt < 12; ++nt) {
        const int sel = nt >> 2, dt = nt & 3;
        #pragma unroll
        for (int c = 0; c < 2; ++c) {
            const bf16x8 b = *(const bf16x8*)&wls[sel][dt * 16 + l16][c * 32 + quad * 8];
            acc[nt] = MFMA16(a[c], b, acc[nt]);
        }
    }

    const float* bias[3] = {bq, bk, bv};
    __bf16* outp[3] = {qo, ko, vo};
    #pragma unroll
    for (int nt = 0; nt < 12; ++nt) {
        const int sel = nt >> 2, dt = nt & 3;
        const float bb = bias[sel][dt * 16 + l16];
        #pragma unroll
        for (int r = 0; r < 4; ++r) {
            const int m = m0 + w * 16 + quad * 4 + r;
            outp[sel][(size_t)m * 64 + dt * 16 + l16] = (__bf16)(acc[nt][r] + bb);
        }
    }
}

// ---------------------------------------------------------------------------
// attn: 512 threads (8 waves), 128 q rows per block, all computed TRANSPOSED
// (per-lane softmax state, lane's l16 = q). Double-buffered K/V tiles with a
// single barrier per k-tile. ps is reused for exp-P, rel scores (wave-private
// rows -> per-wave DS ordering suffices), and the coalescing epilogue.
// ---------------------------------------------------------------------------
__global__ __launch_bounds__(512, 4) void attn_kernel(
    const __bf16* __restrict__ qbf, const __bf16* __restrict__ kbf,
    const __bf16* __restrict__ vbf, const __bf16* __restrict__ erbf,
    __bf16* __restrict__ attnA)
{
    const int bid = blockIdx.x;
    const int p = bid >> 3, qt = bid & 7;   // qt fast -> heavy blocks spread
    const int h = p & 15, n = p >> 4;
    const int q0 = qt * 128;
    const int t = threadIdx.x, w = t >> 6, lane = t & 63;
    const int quad = lane >> 4, l16 = lane & 15;

    __shared__ __bf16 ks[2][64][72];  // K tile row-major (key, d)
    __shared__ __bf16 vt[2][64][72];  // V^T tile: vt[d][key]
    __shared__ __bf16 ps[128][72];    // exp-P / rel / epilogue (wave-private rows)

    const int qw0 = q0 + w * 16;      // this wave's first q row
    const size_t qrowoff = ((size_t)(n * L_ + qw0 + l16) * H_ + h) * D_;
    const bf16x8 qa0 = *(const bf16x8*)(qbf + qrowoff + quad * 8);
    const bf16x8 qa1 = *(const bf16x8*)(qbf + qrowoff + 32 + quad * 8);

    const __bf16* kbase = kbf + ((size_t)n * L_ * H_ + h) * D_;
    const __bf16* vbase = vbf + ((size_t)n * L_ * H_ + h) * D_;
    const int krow = t >> 3, kc8 = (t & 7) * 8;  // K: one float4/thread
    const int vkey = t & 63, vd0 = (t >> 6) * 8; // V: one float4/thread

    // tile 0 -> buf 0, then load tile 1 into regs
    float4 kreg = *(const float4*)(kbase + (size_t)krow * 1024 + kc8);
    float4 vreg = *(const float4*)(vbase + (size_t)vkey * 1024 + vd0);
    *(float4*)&ks[0][krow][kc8] = kreg;
    {
        union { float4 f; __bf16 hv[8]; } u; u.f = vreg;
        #pragma unroll
        for (int j = 0; j < 8; ++j) vt[0][vd0 + j][vkey] = u.hv[j];
    }
    kreg = *(const float4*)(kbase + 64 * 1024 + (size_t)krow * 1024 + kc8);
    vreg = *(const float4*)(vbase + 64 * 1024 + (size_t)vkey * 1024 + vd0);
    __syncthreads();

    const f32x4 zero4 = {0.f, 0.f, 0.f, 0.f};
    f32x4 Os[4], Or[4];
    #pragma unroll
    for (int nt = 0; nt < 4; ++nt) { Os[nt] = zero4; Or[nt] = zero4; }
    float m = -INFINITY, lsum = 0.f;
    const float k2 = 0.03125f * 1.44269504f;  // (1/sqrt(E)) * log2(e)

    for (int kt = 0; kt < 16; ++kt) {
        const int cur = kt & 1;
        if (kt < 15) {
            // store tile kt+1 (already in regs) into the idle buffer; its
            // readers finished before the previous barrier.
            *(float4*)&ks[cur ^ 1][krow][kc8] = kreg;
            union { float4 f; __bf16 hv[8]; } u; u.f = vreg;
            #pragma unroll
            for (int j = 0; j < 8; ++j) vt[cur ^ 1][vd0 + j][vkey] = u.hv[j];
            if (kt < 14) {  // issue loads for tile kt+2; a full iter to land
                const size_t roff = (size_t)(kt + 2) * 64 * 1024;
                kreg = *(const float4*)(kbase + roff + (size_t)krow * 1024 + kc8);
                vreg = *(const float4*)(vbase + roff + (size_t)vkey * 1024 + vd0);
            }
        }

        // ---- S^T = K Q^T (unscaled) ----
        f32x4 sc[4];
        #pragma unroll
        for (int nt = 0; nt < 4; ++nt) {
            f32x4 acc = zero4;
            acc = MFMA16(*(const bf16x8*)&ks[cur][nt * 16 + l16][quad * 8], qa0, acc);
            acc = MFMA16(*(const bf16x8*)&ks[cur][nt * 16 + l16][32 + quad * 8], qa1, acc);
            sc[nt] = acc;
        }

        // ---- online softmax, base 2 (per-lane: this lane's q col = l16) ----
        float mt = sc[0][0];
        #pragma unroll
        for (int nt = 0; nt < 4; ++nt)
            #pragma unroll
            for (int r = 0; r < 4; ++r) mt = fmaxf(mt, sc[nt][r]);
        mt = fmaxf(mt, __shfl_xor(mt, 16, 64));
        mt = fmaxf(mt, __shfl_xor(mt, 32, 64));
        const float mn = fmaxf(m, mt);
        const float alpha = exp2f((m - mn) * k2);
        float esum = 0.f;
        #pragma unroll
        for (int nt = 0; nt < 4; ++nt)
            #pragma unroll
            for (int r = 0; r < 4; ++r) {
                const float e = exp2f((sc[nt][r] - mn) * k2);
                sc[nt][r] = e;
                esum += e;
            }
        esum += __shfl_xor(esum, 16, 64);
        esum += __shfl_xor(esum, 32, 64);
        lsum = lsum * alpha + esum;
        m = mn;
        #pragma unroll
        for (int nt = 0; nt < 4; ++nt) Os[nt] *= alpha;

        // exp-P^T C-frags -> normal-layout ps rows (wave-private)
        #pragma unroll
        for (int nt = 0; nt < 4; ++nt) {
            bf16x4 pk;
            #pragma unroll
            for (int r = 0; r < 4; ++r) pk[r] = (__bf16)sc[nt][r];
            *(bf16x4*)&ps[w * 16 + l16][nt * 16 + quad * 4] = pk;
        }

        // ---- out^T += V^T P^T ----
        {
            const bf16x8 pb0 = *(const bf16x8*)&ps[w * 16 + l16][quad * 8];
            const bf16x8 pb1 = *(const bf16x8*)&ps[w * 16 + l16][32 + quad * 8];
            #pragma unroll
            for (int nt = 0; nt < 4; ++nt) {
                Os[nt] = MFMA16(*(const bf16x8*)&vt[cur][nt * 16 + l16][quad * 8], pb0, Os[nt]);
                Os[nt] = MFMA16(*(const bf16x8*)&vt[cur][nt * 16 + l16][32 + quad * 8], pb1, Os[nt]);
            }
        }

        // ---- relative-position term (only tiles with any k <= q) ----
        if (kt * 64 <= qw0 + 15) {
            const int tb = kt * 64 + 1008 - qw0;   // >= 0 always
            #pragma unroll
            for (int st = 0; st < 5; ++st) {
                int tr = tb + st * 16 + l16;
                tr = tr > 1023 ? 1023 : tr;        // clamped rows masked below
                const __bf16* er = erbf + (size_t)tr * 64;
                f32x4 acc = zero4;
                acc = MFMA16(*(const bf16x8*)(er + quad * 8), qa0, acc);
                acc = MFMA16(*(const bf16x8*)(er + 32 + quad * 8), qa1, acc);
                // skew scatter into ps (overwrites every slot of wave's rows):
                // k-col = st*16+quad*4+r+l16-15 ; masked iff t > 1023
                #pragma unroll
                for (int r = 0; r < 4; ++r) {
                    const int kc = st * 16 + quad * 4 + r + l16 - 15;
                    const int tg = tb + st * 16 + quad * 4 + r;
                    if (kc >= 0 && kc < 64)
                        ps[w * 16 + l16][kc] = (tg <= 1023) ? (__bf16)acc[r]
                                                            : (__bf16)0.0f;
                }
            }
            const bf16x8 rb0 = *(const bf16x8*)&ps[w * 16 + l16][quad * 8];
            const bf16x8 rb1 = *(const bf16x8*)&ps[w * 16 + l16][32 + quad * 8];
            #pragma unroll
            for (int nt = 0; nt < 4; ++nt) {
                Or[nt] = MFMA16(*(const bf16x8*)&vt[cur][nt * 16 + l16][quad * 8], rb0, Or[nt]);
                Or[nt] = MFMA16(*(const bf16x8*)&vt[cur][nt * 16 + l16][32 + quad * 8], rb1, Or[nt]);
            }
        }
        __syncthreads();
    }

    // epilogue: assemble rows in ps (wave-private, no barrier), store 128 B/row
    const float invl = 1.0f / lsum;
    #pragma unroll
    for (int nt = 0; nt < 4; ++nt) {
        bf16x4 ov;
        #pragma unroll
        for (int r = 0; r < 4; ++r)
            ov[r] = (__bf16)(Os[nt][r] * invl + Or[nt][r]);
        *(bf16x4*)&ps[w * 16 + l16][nt * 16 + quad * 4] = ov;
    }
    const int erow = lane >> 3, ec8 = lane & 7;
    #pragma unroll
    for (int i = 0; i < 2; ++i) {
        const int r = erow + i * 8;
        const float4 val = *(const float4*)&ps[w * 16 + r][ec8 * 8];
        *(float4*)(attnA + ((size_t)(n * L_ + qw0 + r)) * E_ + h * 64 + ec8 * 8) = val;
    }
}

// ---------------------------------------------------------------------------
// proj: out (8192 x 1024) f32 = attnA (bf16) @ Wo^T (bf16) + bo.
// m97-style: 128x128 C tile, BK=64, global_load_lds width-16 staging.
// ---------------------------------------------------------------------------
__global__ __launch_bounds__(256) void proj_kernel(
    const __bf16* __restrict__ A, const __bf16* __restrict__ W,
    const float* __restrict__ bo, float* __restrict__ out)
{
    const int bid = blockIdx.x;
    const int rt = bid >> 3, ct = bid & 7;
    const int r0 = rt * 128, c0 = ct * 128;
    const int t = threadIdx.x, w = t >> 6, lane = t & 63;
    const int quad = lane >> 4, l16 = lane & 15;
    const int wm = w >> 1, wn = w & 1;

    __shared__ __bf16 As[128 * 64];   // row-major, 64-col (128 B) rows
    __shared__ __bf16 Bs[128 * 64];

    f32x4 acc[16];
    const f32x4 zero4 = {0.f, 0.f, 0.f, 0.f};
    #pragma unroll
    for (int i = 0; i < 16; ++i) acc[i] = zero4;

    const int lrow = lane >> 3, lcg = lane & 7;

    for (int kt = 0; kt < 16; ++kt) {
        const int e0 = kt * 64;
        __syncthreads();  // prior-iter LDS reads complete
        #pragma unroll
        for (int i = 0; i < 4; ++i) {
            const int chunk = w * 4 + i;           // 8-row chunk, 1 KiB
            const int row = chunk * 8 + lrow;
            const __bf16* ga = A + (size_t)(r0 + row) * E_ + e0 + lcg * 8;
            const __bf16* gb = W + (size_t)(c0 + row) * E_ + e0 + lcg * 8;
            __builtin_amdgcn_global_load_lds(
                (const __attribute__((address_space(1))) void*)ga,
                (__attribute__((address_space(3))) void*)&As[chunk * 512], 16, 0, 0);
            __builtin_amdgcn_global_load_lds(
                (const __attribute__((address_space(1))) void*)gb,
                (__attribute__((address_space(3))) void*)&Bs[chunk * 512], 16, 0, 0);
        }
        __syncthreads();  // drains vmcnt (glds) before reads
        #pragma unroll
        for (int c = 0; c < 2; ++c) {
            bf16x8 am[4], bn[4];
            #pragma unroll
            for (int i = 0; i < 4; ++i) {
                am[i] = *(const bf16x8*)&As[(wm * 64 + i * 16 + l16) * 64 + c * 32 + quad * 8];
                bn[i] = *(const bf16x8*)&Bs[(wn * 64 + i * 16 + l16) * 64 + c * 32 + quad * 8];
            }
            #pragma unroll
            for (int i = 0; i < 4; ++i)
                #pragma unroll
                for (int j = 0; j < 4; ++j)
                    acc[i * 4 + j] = MFMA16(am[i], bn[j], acc[i * 4 + j]);
        }
    }

    #pragma unroll
    for (int i = 0; i < 4; ++i)
        #pragma unroll
        for (int j = 0; j < 4; ++j) {
            const int col = c0 + wn * 64 + j * 16 + l16;
            const float bb = bo[col];
            #pragma unroll
            for (int r = 0; r < 4; ++r)
                out[(size_t)(r0 + wm * 64 + i * 16 + quad * 4 + r) * E_ + col] =
                    acc[i * 4 + j][r] + bb;
        }
}

// ---------------------------------------------------------------------------
extern "C" void kernel_launch(void* const* d_in, const int* in_sizes, int n_in,
                              void* d_out, int out_size, void* d_ws, size_t ws_size,
                              hipStream_t stream)
{
    const float* x    = (const float*)d_in[0];
    const float* Wq   = (const float*)d_in[1];
    const float* bq   = (const float*)d_in[2];
    const float* Wk   = (const float*)d_in[3];
    const float* bk   = (const float*)d_in[4];
    const float* Wv   = (const float*)d_in[5];
    const float* bv   = (const float*)d_in[6];
    const float* Erel = (const float*)d_in[7];
    const float* Wo   = (const float*)d_in[8];
    const float* bo   = (const float*)d_in[9];
    float* out = (float*)d_out;

    char* p = (char*)d_ws;
    __bf16* qbf   = (__bf16*)p; p += (size_t)N_ * L_ * H_ * D_ * 2;  // 16 MB
    __bf16* kbf   = (__bf16*)p; p += (size_t)N_ * L_ * H_ * D_ * 2;
    __bf16* vbf   = (__bf16*)p; p += (size_t)N_ * L_ * H_ * D_ * 2;
    __bf16* attnA = (__bf16*)p; p += (size_t)N_ * L_ * E_ * 2;       // 16 MB
    __bf16* wobf  = (__bf16*)p; p += (size_t)E_ * E_ * 2;            // 2 MB
    __bf16* erbf  = (__bf16*)p; p += (size_t)L_ * D_ * 2;            // 128 KB

    prep_kernel<<<1088, 256, 0, stream>>>(Wo, Erel, wobf, erbf);
    qkv_kernel<<<(N_ * L_ * H_) / 64, 256, 0, stream>>>(x, Wq, bq, Wk, bk, Wv, bv,
                                                        qbf, kbf, vbf);
    attn_kernel<<<N_ * H_ * (L_ / 128), 512, 0, stream>>>(qbf, kbf, vbf, erbf, attnA);
    proj_kernel<<<(N_ * L_ / 128) * (E_ / 128), 256, 0, stream>>>(attnA, wobf, bo, out);
}